// Round 7
// baseline (646.232 us; speedup 1.0000x reference)
//
#include <hip/hip_runtime.h>
#include <hip/hip_bf16.h>

#define B_    8
#define O_    4
#define L_    1024
#define E_    1024
#define BETA_ 512
#define NSEG_ 12
#define BO_   32
#define NCH_  32
#define NBLK  512

// ---- workspace layout (float offsets). ws[0..63] = barrier counters (memset per call).
enum : size_t {
  WS_BAR   = 0,
  WS_SPART = 64,                                       // [32][32][12][1024] sparse chunk partials
  WS_X     = WS_SPART + (size_t)BO_ * NCH_ * 12 * E_,  // [32][13][1024]
  WS_P1P   = WS_X     + (size_t)BO_ * 13 * E_,         // [8][32][13][1024]
  WS_TE    = WS_P1P   + (size_t)8  * BO_ * 13 * E_,    // [32][13][1024]
  WS_H1P   = WS_TE    + (size_t)BO_ * 13 * E_,         // [16][32][10][512]
  WS_T1P   = WS_H1P   + (size_t)16 * BO_ * 10 * BETA_, // [8][32][10][512]
  WS_T1B   = WS_T1P   + (size_t)8  * BO_ * 10 * BETA_, // [32][10][512]
  WS_IAB   = WS_T1B   + (size_t)BO_ * 10 * BETA_,      // [32][1024]
  WS_H2P   = WS_IAB   + (size_t)BO_ * 2 * BETA_,       // [8][32][512]
  WS_T2P   = WS_H2P   + (size_t)8  * BO_ * BETA_,      // [8][32][512]
  WS_RN    = WS_T2P   + (size_t)8  * BO_ * BETA_,      // [32][10][1024]
  WS_H3P   = WS_RN    + (size_t)BO_ * 10 * E_,         // [16][32][10][512]
  WS_T3P   = WS_H3P   + (size_t)16 * BO_ * 10 * BETA_, // [8][32][10][512]
  WS_HFP   = WS_T3P   + (size_t)8  * BO_ * 10 * BETA_, // [32][32][512]
  WS_END   = WS_HFP   + (size_t)32 * BO_ * BETA_,
};

__device__ __forceinline__ float relu_(float v) { return v > 0.f ? v : 0.f; }

// ---- flat grid barrier: 1 threadfence + 1 atomic arrive + relaxed spin PER BLOCK ----
__device__ __forceinline__ void gbar(unsigned* bar, unsigned tgt, int tid) {
    __syncthreads();                 // all waves: vmcnt drained before fence
    if (tid == 0) {
        __threadfence();             // one L2 writeback/inv per block (device scope)
        __hip_atomic_fetch_add(bar, 1u, __ATOMIC_RELAXED, __HIP_MEMORY_SCOPE_AGENT);
        while (__hip_atomic_load(bar, __ATOMIC_RELAXED, __HIP_MEMORY_SCOPE_AGENT) < tgt)
            __builtin_amdgcn_s_sleep(16);
        __threadfence();             // acquire side: invalidate L1/L2 once per block
    }
    __syncthreads();
}

// ---- split-K GEMM task (round-5 proven): partial-slice out, fused x-loader ----------
// XF 0 identity | 1 TE=1+relu(ΣXp+b), side TE | 2 relu(ΣXp+b) | 4 pool1->IAB (side T1B,IAB)
// XF 5 pool2->RN (side RN) | 6 pool3+cat
template<int M, int ML, int K, int N, int KC, int BOG, int XF, int NPART>
__device__ void gemm_phase(
    const int gid, const int tid, const int NT, float* xs,
    const float* __restrict__ Xb, const float* __restrict__ xbias,
    const float* __restrict__ W, float* __restrict__ OUT,
    const float* __restrict__ A0, const float* __restrict__ A1,
    const float* __restrict__ A2, const float* __restrict__ A3,
    float* __restrict__ SIDE, float* __restrict__ SIDE2) {
    constexpr int NCH = N / 256;
    constexpr int NBOG = BO_ / BOG;
    for (int task = gid; task < NT; task += NBLK) {
        const int nidx = task % NCH;
        const int rest = task / NCH;
        const int bidx = rest % NBOG;
        const int kidx = rest / NBOG;
        const int k0 = kidx * KC;
        const int bo0 = bidx * BOG;
        const int c = nidx * 256 + tid;

        for (int i = tid; i < BOG * ML * KC; i += 256) {
            const int kk = i % KC;
            const int rm = i / KC;
            const int m = rm % ML;
            const int bb = rm / ML;
            const int bo = bo0 + bb;
            const int k = k0 + kk;
            float v;
            if constexpr (XF == 0) {
                v = Xb[((size_t)bo * ML + m) * K + k];
            } else if constexpr (XF == 1) {
                float s = xbias[k];
#pragma unroll
                for (int p = 0; p < NPART; ++p)
                    s += Xb[(((size_t)p * BO_ + bo) * ML + m) * K + k];
                v = 1.f + relu_(s);
                SIDE[((size_t)bo * ML + m) * K + k] = v;  // TE (all 13 rows)
            } else if constexpr (XF == 2) {
                float s = xbias[k];
#pragma unroll
                for (int p = 0; p < NPART; ++p)
                    s += Xb[(((size_t)p * BO_ + bo) * ML + m) * K + k];
                v = relu_(s);
            } else if constexpr (XF == 4) {
                const int col = k & 511, half = k >> 9;
                const float bac = A2[col];
                float t[10], mx = -1e30f;
#pragma unroll
                for (int j = 0; j < 10; ++j) {
                    float s = bac;
#pragma unroll
                    for (int p = 0; p < NPART; ++p)
                        s += A0[(((size_t)p * BO_ + bo) * 10 + j) * BETA_ + col];
                    t[j] = s;
                    mx = fmaxf(mx, s);
                }
                if (half == 0) {
#pragma unroll
                    for (int j = 0; j < 10; ++j)
                        SIDE2[((size_t)bo * 10 + j) * BETA_ + col] = t[j];  // T1B
                }
                float sw = 0.f, acc = 0.f;
#pragma unroll
                for (int j = 0; j < 10; ++j) {
                    const float pj = expf(t[j] - mx);
                    sw += pj;
                    acc = fmaf(pj, A1[((size_t)bo * 13 + j) * E_ + half * BETA_ + col], acc);
                }
                v = acc / sw;
                SIDE[(size_t)bo * 1024 + k] = v;  // IAB
            } else if constexpr (XF == 5) {
                const int col = k & 511, half = k >> 9;
                const float tj = A0[((size_t)bo * 10 + m) * BETA_ + col];  // T1B
                float tI = A2[col];
#pragma unroll
                for (int p = 0; p < NPART; ++p)
                    tI += A1[((size_t)p * BO_ + bo) * BETA_ + col];
                const float mx = fmaxf(tj, tI);
                const float e0 = expf(tj - mx);
                const float e1 = expf(tI - mx);
                const float ea = A3[((size_t)bo * 13 + m) * E_ + half * BETA_ + col];  // TE
                const float iv = SIDE2[(size_t)bo * 1024 + k];                         // IAB
                v = (e0 + e1) / (e0 * ea + e1 * iv);
                SIDE[((size_t)bo * 10 + m) * E_ + k] = v;  // RN
            } else {  // XF == 6
                if (k < 1024) {
                    const int col = k & 511;
                    const float bac = A2[col];
                    float t[10], mx = -1e30f;
#pragma unroll
                    for (int j = 0; j < 10; ++j) {
                        float s = bac;
#pragma unroll
                        for (int p = 0; p < NPART; ++p)
                            s += A0[(((size_t)p * BO_ + bo) * 10 + j) * BETA_ + col];
                        t[j] = s;
                        mx = fmaxf(mx, s);
                    }
                    float sw = 0.f, acc = 0.f;
#pragma unroll
                    for (int j = 0; j < 10; ++j) {
                        const float pj = expf(t[j] - mx);
                        sw += pj;
                        acc = fmaf(pj, A1[((size_t)bo * 10 + j) * E_ + k], acc);  // RN
                    }
                    v = sw / acc;
                } else {
                    const int region = k >> 10;
                    const int row = (region == 1) ? 12 : (region == 2) ? 11 : 10;
                    v = A3[((size_t)bo * 13 + row) * E_ + (k & 1023)];  // TE rows
                }
            }
            xs[i] = v;
        }
        __syncthreads();

        float acc[BOG][M];
#pragma unroll
        for (int b = 0; b < BOG; ++b)
#pragma unroll
            for (int m = 0; m < M; ++m) acc[b][m] = 0.f;
        const float* __restrict__ wp = W + (size_t)k0 * N + c;
        for (int k4 = 0; k4 < KC / 4; ++k4) {
            const float w0 = wp[(size_t)(4 * k4 + 0) * N];
            const float w1 = wp[(size_t)(4 * k4 + 1) * N];
            const float w2 = wp[(size_t)(4 * k4 + 2) * N];
            const float w3 = wp[(size_t)(4 * k4 + 3) * N];
#pragma unroll
            for (int b = 0; b < BOG; ++b) {
#pragma unroll
                for (int m = 0; m < M; ++m) {
                    const float4 xv = *reinterpret_cast<const float4*>(&xs[(b * ML + m) * KC + 4 * k4]);
                    float a = acc[b][m];
                    a = fmaf(xv.x, w0, a);
                    a = fmaf(xv.y, w1, a);
                    a = fmaf(xv.z, w2, a);
                    a = fmaf(xv.w, w3, a);
                    acc[b][m] = a;
                }
            }
        }
#pragma unroll
        for (int b = 0; b < BOG; ++b) {
            float* op = OUT + (((size_t)kidx * BO_ + bo0 + b) * M) * N + c;
#pragma unroll
            for (int m = 0; m < M; ++m) op[(size_t)m * N] = acc[b][m];
        }
        __syncthreads();  // xs WAR before next task
    }
}

__global__ void __launch_bounds__(256, 2) pipeline(
    const float* __restrict__ hidden, const int* __restrict__ idx,
    const float* __restrict__ Wp, const float* __restrict__ bp,
    const float* __restrict__ Wa0, const float* __restrict__ ba0,
    const float* __restrict__ Wa, const float* __restrict__ ba,
    const float* __restrict__ Wl0, const float* __restrict__ bl0,
    const float* __restrict__ Wl, const float* __restrict__ bl,
    float* __restrict__ ws, float* __restrict__ out) {
    const int gid = blockIdx.x;
    const int tid = threadIdx.x;
    __shared__ __align__(16) float xs[2 * 13 * 128];  // 13.3 KB, reused all phases

    unsigned* bar = reinterpret_cast<unsigned*>(ws + WS_BAR);
    float* SPART = ws + WS_SPART;
    float* X     = ws + WS_X;
    float* P1P   = ws + WS_P1P;
    float* TE    = ws + WS_TE;
    float* H1P   = ws + WS_H1P;
    float* T1P   = ws + WS_T1P;
    float* T1B   = ws + WS_T1B;
    float* IAB   = ws + WS_IAB;
    float* H2P   = ws + WS_H2P;
    float* T2P   = ws + WS_T2P;
    float* RN    = ws + WS_RN;
    float* H3P   = ws + WS_H3P;
    float* T3P   = ws + WS_T3P;
    float* HFP   = ws + WS_HFP;
    const float* NUL = nullptr;

    // ---- P1: k1 segment partial sums (1024 tasks) -----------------------------------
    for (int task = gid; task < NCH_ * BO_; task += NBLK) {
        const int chunk = task & (NCH_ - 1);
        const int bo = task >> 5;
        const int b = bo >> 2;
        int cuts[13];
        cuts[0] = 1;
#pragma unroll
        for (int i = 0; i < 12; ++i) cuts[i + 1] = idx[b * NSEG_ + i];
        const int l0 = chunk * 32;
        const int l1 = l0 + 32;
        int lo = l0 < 1 ? 1 : l0;
        const int hi = l1 < cuts[12] ? l1 : cuts[12];
        if (lo >= hi) continue;
        const int e4 = tid << 2;
        const float* base = hidden + (size_t)bo * (L_ * E_) + e4;
        float* sp = SPART + (size_t)(bo * NCH_ + chunk) * 12 * E_ + e4;
        int j = 0;
        while (j < 11 && cuts[j + 1] <= lo) ++j;
        int l = lo;
        while (l < hi) {
            const int e2 = (j < 11 && cuts[j + 1] < hi) ? cuts[j + 1] : hi;
            float sx = 0.f, sy = 0.f, sz = 0.f, sw = 0.f;
            for (; l < e2; ++l) {
                const float4 v = *reinterpret_cast<const float4*>(base + (size_t)l * E_);
                sx += v.x; sy += v.y; sz += v.z; sw += v.w;
            }
            float4 s; s.x = sx; s.y = sy; s.z = sz; s.w = sw;
            *reinterpret_cast<float4*>(sp + (size_t)j * E_) = s;
            ++j;
        }
    }
    gbar(bar, NBLK * 1, tid);

    // ---- P2: k2 means (128 tasks) ----------------------------------------------------
    for (int task = gid; task < 128; task += NBLK) {
        const int bo = task >> 2;
        const int col = (task & 3) * 256 + tid;
        const int b = bo >> 2;
        int cuts[13];
        cuts[0] = 1;
#pragma unroll
        for (int i = 0; i < 12; ++i) cuts[i + 1] = idx[b * NSEG_ + i];
        const float* sp = SPART + (size_t)bo * NCH_ * 12 * E_ + col;
        float allc = 0.f;
#pragma unroll
        for (int m = 0; m < 12; ++m) {
            const int c0 = cuts[m] >> 5;
            const int c1 = (cuts[m + 1] - 1) >> 5;
            float s = 0.f;
            for (int ch = c0; ch <= c1; ++ch) s += sp[((size_t)ch * 12 + m) * E_];
            X[((size_t)bo * 13 + m) * E_ + col] = s / (float)(cuts[m + 1] - cuts[m]);
            if (m < 10) allc += s;
        }
        X[((size_t)bo * 13 + 12) * E_ + col] = allc / (float)(cuts[10] - 1);
    }
    gbar(bar, NBLK * 2, tid);

    // ---- P3..P10: the GEMM chain -----------------------------------------------------
    gemm_phase<13, 13, 1024, 1024, 128, 2, 0, 1>(gid, tid, 512, xs, X, NUL, Wp, P1P,
                                                 NUL, NUL, NUL, NUL, nullptr, nullptr);
    gbar(bar, NBLK * 3, tid);
    gemm_phase<10, 13, 1024, 512, 64, 2, 1, 8>(gid, tid, 512, xs, P1P, bp, Wa0, H1P,
                                               NUL, NUL, NUL, NUL, TE, nullptr);
    gbar(bar, NBLK * 4, tid);
    gemm_phase<10, 10, 512, 512, 64, 2, 2, 16>(gid, tid, 256, xs, H1P, ba0, Wa, T1P,
                                               NUL, NUL, NUL, NUL, nullptr, nullptr);
    gbar(bar, NBLK * 5, tid);
    gemm_phase<1, 1, 1024, 512, 128, 8, 4, 8>(gid, tid, 64, xs, NUL, NUL, Wa0, H2P,
                                              T1P, TE, ba, NUL, IAB, T1B);
    gbar(bar, NBLK * 6, tid);
    gemm_phase<1, 1, 512, 512, 64, 8, 2, 8>(gid, tid, 64, xs, H2P, ba0, Wa, T2P,
                                            NUL, NUL, NUL, NUL, nullptr, nullptr);
    gbar(bar, NBLK * 7, tid);
    gemm_phase<10, 10, 1024, 512, 64, 2, 5, 8>(gid, tid, 512, xs, NUL, NUL, Wa0, H3P,
                                               T1B, T2P, ba, TE, RN, IAB);
    gbar(bar, NBLK * 8, tid);
    gemm_phase<10, 10, 512, 512, 64, 2, 2, 16>(gid, tid, 256, xs, H3P, ba0, Wa, T3P,
                                               NUL, NUL, NUL, NUL, nullptr, nullptr);
    gbar(bar, NBLK * 9, tid);
    gemm_phase<1, 1, 4096, 512, 128, 8, 6, 8>(gid, tid, 256, xs, NUL, NUL, Wl0, HFP,
                                              T3P, RN, ba, TE, nullptr, nullptr);
    gbar(bar, NBLK * 10, tid);

    // ---- P11: k_final (32 tasks) -----------------------------------------------------
    for (int task = gid; task < BO_; task += NBLK) {
        const int bo = task;
        float partial = 0.f;
#pragma unroll
        for (int h = 0; h < 2; ++h) {
            const int c = h * 256 + tid;
            float s = bl0[c];
#pragma unroll
            for (int p = 0; p < 32; ++p) s += HFP[((size_t)p * BO_ + bo) * BETA_ + c];
            partial = fmaf(relu_(s), Wl[c], partial);
        }
#pragma unroll
        for (int off = 32; off > 0; off >>= 1) partial += __shfl_down(partial, off, 64);
        __syncthreads();
        if ((tid & 63) == 0) xs[tid >> 6] = partial;
        __syncthreads();
        if (tid == 0) out[bo] = xs[0] + xs[1] + xs[2] + xs[3] + bl[0];
        __syncthreads();
    }
}

extern "C" void kernel_launch(void* const* d_in, const int* in_sizes, int n_in,
                              void* d_out, int out_size, void* d_ws, size_t ws_size,
                              hipStream_t stream) {
    const float* hidden = (const float*)d_in[0];
    const int* idx = (const int*)d_in[1];
    const float* Wp  = (const float*)d_in[2];
    const float* bp  = (const float*)d_in[3];
    const float* Wa0 = (const float*)d_in[4];
    const float* ba0 = (const float*)d_in[5];
    const float* Wa  = (const float*)d_in[6];
    const float* ba  = (const float*)d_in[7];
    const float* Wl0 = (const float*)d_in[8];
    const float* bl0 = (const float*)d_in[9];
    const float* Wl  = (const float*)d_in[10];
    const float* bl  = (const float*)d_in[11];
    float* ws = (float*)d_ws;
    float* out = (float*)d_out;

    hipMemsetAsync(d_ws, 0, 256, stream);  // zero barrier counters
    void* kargs[] = {
        (void*)&hidden, (void*)&idx, (void*)&Wp, (void*)&bp,
        (void*)&Wa0, (void*)&ba0, (void*)&Wa, (void*)&ba,
        (void*)&Wl0, (void*)&bl0, (void*)&Wl, (void*)&bl,
        (void*)&ws, (void*)&out,
    };
    hipLaunchCooperativeKernel((const void*)pipeline, dim3(NBLK), dim3(256), kargs, 0, stream);
}

// Round 8
// 359.008 us; speedup vs baseline: 1.8000x; 1.8000x over previous
//
#include <hip/hip_runtime.h>
#include <hip/hip_bf16.h>

#define B_    8
#define O_    4
#define L_    1024
#define E_    1024
#define BETA_ 512
#define NSEG_ 12
#define BO_   32
#define NCH_  32   // k1: 32-row chunks, 32 per bo

// ---- workspace layout (float offsets). NO zero-init needed anywhere.
enum : size_t {
  WS_SPART = 0,                                        // [32][32][12][1024] sparse chunk partials
  WS_X     = WS_SPART + (size_t)BO_ * NCH_ * 12 * E_,  // [32][13][1024]
  WS_P1P   = WS_X     + (size_t)BO_ * 13 * E_,         // [16][32][13][1024]
  WS_TE    = WS_P1P   + (size_t)16 * BO_ * 13 * E_,    // [32][13][1024]  1+relu(P1+bp)
  WS_H1P   = WS_TE    + (size_t)BO_ * 13 * E_,         // [16][32][10][512]
  WS_H1R   = WS_H1P   + (size_t)16 * BO_ * 10 * BETA_, // [32][10][512]
  WS_T1P   = WS_H1R   + (size_t)BO_ * 10 * BETA_,      // [16][32][10][512]
  WS_T1B   = WS_T1P   + (size_t)16 * BO_ * 10 * BETA_, // [32][10][512]
  WS_IAB   = WS_T1B   + (size_t)BO_ * 10 * BETA_,      // [32][1024]
  WS_H2P   = WS_IAB   + (size_t)BO_ * 2 * BETA_,       // [16][32][512]
  WS_H2R   = WS_H2P   + (size_t)16 * BO_ * BETA_,      // [32][512]
  WS_T2P   = WS_H2R   + (size_t)BO_ * BETA_,           // [16][32][512]
  WS_RN    = WS_T2P   + (size_t)16 * BO_ * BETA_,      // [32][10][1024]
  WS_H3P   = WS_RN    + (size_t)BO_ * 10 * E_,         // [16][32][10][512]
  WS_H3R   = WS_H3P   + (size_t)16 * BO_ * 10 * BETA_, // [32][10][512]
  WS_T3P   = WS_H3R   + (size_t)BO_ * 10 * BETA_,      // [16][32][10][512]
  WS_CAT   = WS_T3P   + (size_t)16 * BO_ * 10 * BETA_, // [32][4096]
  WS_HFP   = WS_CAT   + (size_t)BO_ * 8 * BETA_,       // [32][32][512]
  WS_END   = WS_HFP   + (size_t)32 * BO_ * BETA_,
};

__device__ __forceinline__ float relu_(float v) { return v > 0.f ? v : 0.f; }

// ---------------- K1: overlap-aware per-chunk segment partial sums --------------------
__global__ void k1_segsum(const float* __restrict__ hidden, const int* __restrict__ idx,
                          float* __restrict__ Spart) {
    const int chunk = blockIdx.x;  // 0..31, 32 rows each
    const int bo = blockIdx.y;
    const int b = bo >> 2;
    int cuts[13];
    cuts[0] = 1;
#pragma unroll
    for (int i = 0; i < 12; ++i) cuts[i + 1] = idx[b * NSEG_ + i];
    const int l0 = chunk * 32;
    const int l1 = l0 + 32;
    int lo = l0 < 1 ? 1 : l0;
    const int hi = l1 < cuts[12] ? l1 : cuts[12];
    if (lo >= hi) return;
    const int e4 = threadIdx.x << 2;
    const float* base = hidden + (size_t)bo * (L_ * E_) + e4;
    float* sp = Spart + (size_t)(bo * NCH_ + chunk) * 12 * E_ + e4;
    int j = 0;
    while (j < 11 && cuts[j + 1] <= lo) ++j;
    int l = lo;
    while (l < hi) {
        const int e2 = (j < 11 && cuts[j + 1] < hi) ? cuts[j + 1] : hi;
        float sx = 0.f, sy = 0.f, sz = 0.f, sw = 0.f;
        for (; l < e2; ++l) {
            const float4 v = *reinterpret_cast<const float4*>(base + (size_t)l * E_);
            sx += v.x; sy += v.y; sz += v.z; sw += v.w;
        }
        float4 s; s.x = sx; s.y = sy; s.z = sz; s.w = sw;
        *reinterpret_cast<float4*>(sp + (size_t)j * E_) = s;
        ++j;
    }
}

// ---------------- K2: reduce intersecting chunk partials -> means ---------------------
__global__ __launch_bounds__(256) void k2_means(
    const float* __restrict__ Spart, const int* __restrict__ idx,
    float* __restrict__ X) {
    const int bo = blockIdx.y;
    const int col = blockIdx.x * 256 + threadIdx.x;
    const int b = bo >> 2;
    int cuts[13];
    cuts[0] = 1;
#pragma unroll
    for (int i = 0; i < 12; ++i) cuts[i + 1] = idx[b * NSEG_ + i];
    const float* sp = Spart + (size_t)bo * NCH_ * 12 * E_ + col;
    float allc = 0.f;
#pragma unroll
    for (int m = 0; m < 12; ++m) {
        const int c0 = cuts[m] >> 5;
        const int c1 = (cuts[m + 1] - 1) >> 5;
        float s = 0.f;
        for (int ch = c0; ch <= c1; ++ch) s += sp[((size_t)ch * 12 + m) * E_];
        X[((size_t)bo * 13 + m) * E_ + col] = s / (float)(cuts[m + 1] - cuts[m]);
        if (m < 10) allc += s;
    }
    X[((size_t)bo * 13 + 12) * E_ + col] = allc / (float)(cuts[10] - 1);
}

// ---- wide-BOG split-K GEMM: acc registers absorb bo-reuse; weights read 32/BOG x ----
// OUTP[((kidx*32 + bo)*M + m)*N + c] = sum_{k in slice} XR[(bo*XM+m)*K+k] * W[k*N+c]
template<int M, int XM, int K, int N, int KC, int BOG>
__global__ __launch_bounds__(256) void gemm_w(
    const float* __restrict__ XR, const float* __restrict__ W,
    float* __restrict__ OUTP) {
    const int kidx = blockIdx.x;
    const int k0 = kidx * KC;
    const int bo0 = blockIdx.y * BOG;
    const int c = blockIdx.z * 256 + threadIdx.x;
    float acc[BOG][M];
#pragma unroll
    for (int b = 0; b < BOG; ++b)
#pragma unroll
        for (int m = 0; m < M; ++m) acc[b][m] = 0.f;
    const float* __restrict__ wp = W + (size_t)k0 * N + c;
    const float* __restrict__ xp = XR + (size_t)bo0 * XM * K + k0;
    for (int k4 = 0; k4 < KC / 4; ++k4) {
        const float w0 = wp[(size_t)(4 * k4 + 0) * N];
        const float w1 = wp[(size_t)(4 * k4 + 1) * N];
        const float w2 = wp[(size_t)(4 * k4 + 2) * N];
        const float w3 = wp[(size_t)(4 * k4 + 3) * N];
#pragma unroll
        for (int b = 0; b < BOG; ++b) {
#pragma unroll
            for (int m = 0; m < M; ++m) {
                const float4 xv = *reinterpret_cast<const float4*>(
                    xp + ((size_t)b * XM + m) * K + 4 * k4);
                float a = acc[b][m];
                a = fmaf(xv.x, w0, a);
                a = fmaf(xv.y, w1, a);
                a = fmaf(xv.z, w2, a);
                a = fmaf(xv.w, w3, a);
                acc[b][m] = a;
            }
        }
    }
#pragma unroll
    for (int b = 0; b < BOG; ++b) {
        float* op = OUTP + (((size_t)kidx * BO_ + bo0 + b) * M) * N + c;
#pragma unroll
        for (int m = 0; m < M; ++m) op[(size_t)m * N] = acc[b][m];
    }
}

// ---------------- t_te: TE = 1+relu(sum P1P + bp); fills CAT rows 10..12 --------------
__global__ __launch_bounds__(256) void t_te(
    const float* __restrict__ P1P, const float* __restrict__ bp,
    float* __restrict__ TE, float* __restrict__ CAT) {
    const int bo = blockIdx.y;
    const int i = blockIdx.x * 256 + threadIdx.x;  // < 13*1024
    const int m = i >> 10, col = i & 1023;
    float s = bp[col];
#pragma unroll
    for (int p = 0; p < 16; ++p)
        s += P1P[(((size_t)p * BO_ + bo) * 13 + m) * E_ + col];
    const float v = 1.f + relu_(s);
    TE[((size_t)bo * 13 + m) * E_ + col] = v;
    if (m >= 10) CAT[(size_t)bo * 4096 + (size_t)(13 - m) * 1024 + col] = v;
}

// ---------------- t_hrelu: HR = relu(sum_p HP + b) ------------------------------------
template<int NPART, int ROWS>
__global__ __launch_bounds__(256) void t_hrelu(
    const float* __restrict__ HP, const float* __restrict__ b,
    float* __restrict__ HR) {
    const int bo = blockIdx.y;
    const int i = blockIdx.x * 256 + threadIdx.x;  // < ROWS*512
    const int col = i & 511;
    float s = b[col];
#pragma unroll
    for (int p = 0; p < NPART; ++p)
        s += HP[((size_t)p * BO_ + bo) * (ROWS * BETA_) + i];
    HR[(size_t)bo * (ROWS * BETA_) + i] = relu_(s);
}

// ---------------- t_iab: pool-1 logits + softmax -> T1B, IAB --------------------------
__global__ void __launch_bounds__(512) t_iab(
    const float* __restrict__ T1P, const float* __restrict__ ba,
    const float* __restrict__ TE, float* __restrict__ T1B,
    float* __restrict__ IAB) {
    const int bo = blockIdx.x;
    const int c = threadIdx.x;  // 0..511
    const float bac = ba[c];
    float t[10], mx = -1e30f;
#pragma unroll
    for (int j = 0; j < 10; ++j) {
        float s = bac;
#pragma unroll
        for (int p = 0; p < 16; ++p)
            s += T1P[(((size_t)p * BO_ + bo) * 10 + j) * BETA_ + c];
        t[j] = s;
        T1B[((size_t)bo * 10 + j) * BETA_ + c] = s;
        mx = fmaxf(mx, s);
    }
    float p[10], sw = 0.f;
#pragma unroll
    for (int j = 0; j < 10; ++j) { p[j] = expf(t[j] - mx); sw += p[j]; }
    const float inv = 1.0f / sw;
    float ia = 0.f, ib = 0.f;
#pragma unroll
    for (int j = 0; j < 10; ++j) {
        const float pj = p[j] * inv;
        ia = fmaf(pj, TE[((size_t)bo * 13 + j) * E_ + c], ia);
        ib = fmaf(pj, TE[((size_t)bo * 13 + j) * E_ + BETA_ + c], ib);
    }
    IAB[(size_t)bo * 1024 + c] = ia;
    IAB[(size_t)bo * 1024 + BETA_ + c] = ib;
}

// ---------------- t_rn: pool-2 2-way softmax -> RN ------------------------------------
__global__ __launch_bounds__(256) void t_rn(
    const float* __restrict__ T1B, const float* __restrict__ T2P,
    const float* __restrict__ ba, const float* __restrict__ TE,
    const float* __restrict__ IAB, float* __restrict__ RN) {
    const int bo = blockIdx.y;
    const int i = blockIdx.x * 256 + threadIdx.x;  // j*1024 + k
    const int j = i >> 10, k = i & 1023;
    const int col = k & 511;
    const float tj = T1B[((size_t)bo * 10 + j) * BETA_ + col];
    float tI = ba[col];
#pragma unroll
    for (int p = 0; p < 16; ++p)
        tI += T2P[((size_t)p * BO_ + bo) * BETA_ + col];
    const float mx = fmaxf(tj, tI);
    const float e0 = expf(tj - mx);
    const float e1 = expf(tI - mx);
    const float ea = TE[((size_t)bo * 13 + j) * E_ + k];
    const float iv = IAB[(size_t)bo * 1024 + k];
    RN[((size_t)bo * 10 + j) * E_ + k] = (e0 + e1) / (e0 * ea + e1 * iv);
}

// ---------------- t_cat: pool-3 softmax -> CAT cols 0..1023 ---------------------------
__global__ __launch_bounds__(256) void t_cat(
    const float* __restrict__ T3P, const float* __restrict__ ba,
    const float* __restrict__ RN, float* __restrict__ CAT) {
    const int bo = blockIdx.y;
    const int k = blockIdx.x * 256 + threadIdx.x;  // < 1024
    const int col = k & 511;
    const float bac = ba[col];
    float t[10], mx = -1e30f;
#pragma unroll
    for (int j = 0; j < 10; ++j) {
        float s = bac;
#pragma unroll
        for (int p = 0; p < 16; ++p)
            s += T3P[(((size_t)p * BO_ + bo) * 10 + j) * BETA_ + col];
        t[j] = s;
        mx = fmaxf(mx, s);
    }
    float sw = 0.f, acc = 0.f;
#pragma unroll
    for (int j = 0; j < 10; ++j) {
        const float pj = expf(t[j] - mx);
        sw += pj;
        acc = fmaf(pj, RN[((size_t)bo * 10 + j) * E_ + k], acc);
    }
    CAT[(size_t)bo * 4096 + k] = sw / acc;
}

// ---------------- final: out[bo] = relu(sum_p HFpart + bl0) . Wl + bl -----------------
__global__ void __launch_bounds__(512) k_final(
    const float* __restrict__ HFP, const float* __restrict__ bl0,
    const float* __restrict__ Wl, const float* __restrict__ bl,
    float* __restrict__ out) {
    const int bo = blockIdx.x;
    const int c = threadIdx.x;
    float s = bl0[c];
#pragma unroll
    for (int p = 0; p < 32; ++p) s += HFP[((size_t)p * BO_ + bo) * BETA_ + c];
    float partial = relu_(s) * Wl[c];
#pragma unroll
    for (int off = 32; off > 0; off >>= 1) partial += __shfl_down(partial, off, 64);
    __shared__ float red[8];
    if ((c & 63) == 0) red[c >> 6] = partial;
    __syncthreads();
    if (c == 0) out[bo] = red[0] + red[1] + red[2] + red[3] + red[4] + red[5] + red[6] + red[7] + bl[0];
}

extern "C" void kernel_launch(void* const* d_in, const int* in_sizes, int n_in,
                              void* d_out, int out_size, void* d_ws, size_t ws_size,
                              hipStream_t stream) {
    const float* hidden = (const float*)d_in[0];
    const int* idx = (const int*)d_in[1];
    const float* Wp  = (const float*)d_in[2];
    const float* bp  = (const float*)d_in[3];
    const float* Wa0 = (const float*)d_in[4];
    const float* ba0 = (const float*)d_in[5];
    const float* Wa  = (const float*)d_in[6];
    const float* ba  = (const float*)d_in[7];
    const float* Wl0 = (const float*)d_in[8];
    const float* bl0 = (const float*)d_in[9];
    const float* Wl  = (const float*)d_in[10];
    const float* bl  = (const float*)d_in[11];
    float* ws = (float*)d_ws;
    float* SPART = ws + WS_SPART;
    float* X     = ws + WS_X;
    float* P1P   = ws + WS_P1P;
    float* TE    = ws + WS_TE;
    float* H1P   = ws + WS_H1P;
    float* H1R   = ws + WS_H1R;
    float* T1P   = ws + WS_T1P;
    float* T1B   = ws + WS_T1B;
    float* IAB   = ws + WS_IAB;
    float* H2P   = ws + WS_H2P;
    float* H2R   = ws + WS_H2R;
    float* T2P   = ws + WS_T2P;
    float* RN    = ws + WS_RN;
    float* H3P   = ws + WS_H3P;
    float* H3R   = ws + WS_H3R;
    float* T3P   = ws + WS_T3P;
    float* CAT   = ws + WS_CAT;
    float* HFP   = ws + WS_HFP;

    k1_segsum<<<dim3(NCH_, BO_), 256, 0, stream>>>(hidden, idx, SPART);
    k2_means<<<dim3(4, BO_), 256, 0, stream>>>(SPART, idx, X);
    // G1: P1P[16] = X @ Wp  (M=13, K=1024, N=1024)  BOG=8 -> weights x4
    gemm_w<13, 13, 1024, 1024, 64, 8>
        <<<dim3(16, 4, 4), 256, 0, stream>>>(X, Wp, P1P);
    t_te<<<dim3(52, BO_), 256, 0, stream>>>(P1P, bp, TE, CAT);
    // G2: H1P[16] = TE(rows 0..9) @ Wa0  BOG=4 -> weights x8
    gemm_w<10, 13, 1024, 512, 64, 4>
        <<<dim3(16, 8, 2), 256, 0, stream>>>(TE, Wa0, H1P);
    t_hrelu<16, 10><<<dim3(20, BO_), 256, 0, stream>>>(H1P, ba0, H1R);
    // G3: T1P[16] = H1R @ Wa  (K=512)
    gemm_w<10, 10, 512, 512, 32, 4>
        <<<dim3(16, 8, 2), 256, 0, stream>>>(H1R, Wa, T1P);
    t_iab<<<BO_, 512, 0, stream>>>(T1P, ba, TE, T1B, IAB);
    // G4: H2P[16] = IAB @ Wa0  (M=1) BOG=8
    gemm_w<1, 1, 1024, 512, 64, 8>
        <<<dim3(16, 4, 2), 256, 0, stream>>>(IAB, Wa0, H2P);
    t_hrelu<16, 1><<<dim3(2, BO_), 256, 0, stream>>>(H2P, ba0, H2R);
    // G5: T2P[16] = H2R @ Wa  (M=1, K=512) BOG=8
    gemm_w<1, 1, 512, 512, 32, 8>
        <<<dim3(16, 4, 2), 256, 0, stream>>>(H2R, Wa, T2P);
    t_rn<<<dim3(40, BO_), 256, 0, stream>>>(T1B, T2P, ba, TE, IAB, RN);
    // G6: H3P[16] = RN @ Wa0
    gemm_w<10, 10, 1024, 512, 64, 4>
        <<<dim3(16, 8, 2), 256, 0, stream>>>(RN, Wa0, H3P);
    t_hrelu<16, 10><<<dim3(20, BO_), 256, 0, stream>>>(H3P, ba0, H3R);
    // G7: T3P[16] = H3R @ Wa
    gemm_w<10, 10, 512, 512, 32, 4>
        <<<dim3(16, 8, 2), 256, 0, stream>>>(H3R, Wa, T3P);
    t_cat<<<dim3(4, BO_), 256, 0, stream>>>(T3P, ba, RN, CAT);
    // G8: HFP[32] = CAT @ Wl0  (M=1, K=4096) BOG=16 -> weights x2
    gemm_w<1, 1, 4096, 512, 128, 16>
        <<<dim3(32, 2, 2), 256, 0, stream>>>(CAT, Wl0, HFP);
    k_final<<<BO_, 512, 0, stream>>>(HFP, bl0, Wl, bl, (float*)d_out);
}